// Round 1
// baseline (455.708 us; speedup 1.0000x reference)
//
#include <hip/hip_runtime.h>
#include <math.h>

// Problem constants (match reference setup_inputs)
#define BB 64
#define TT 512
#define VV 1296
#define SS 32
#define LL 65            // 2*S+1 extended labels
#define LP 72            // padded row stride for lp_ext (16B-aligned rows)
#define NEGV (-1e30f)

// ---------------------------------------------------------------------------
// Kernel 1: per (b,t) row — log-softmax normalizer + gather of the 65
// extended-label log-probs into ws. One block of 256 threads per row.
// Row = 1296 floats = 324 float4; thread t loads float4 t and (256+t) (t<68).
// ---------------------------------------------------------------------------
__global__ __launch_bounds__(256) void k_lse_gather(
    const float* __restrict__ logits,
    const int* __restrict__ targets,
    float* __restrict__ lp_ext)
{
    const int bt  = blockIdx.x;          // b*T + t
    const int b   = bt / TT;
    const int tid = threadIdx.x;

    const float* row = logits + (size_t)bt * VV;
    const float4* row4 = (const float4*)row;

    float4 v0 = row4[tid];
    const bool has2 = tid < (VV / 4 - 256);   // 324 - 256 = 68
    float4 v1 = has2 ? row4[256 + tid]
                     : make_float4(-INFINITY, -INFINITY, -INFINITY, -INFINITY);

    // ---- block max ----
    float m = fmaxf(fmaxf(v0.x, v0.y), fmaxf(v0.z, v0.w));
    m = fmaxf(m, fmaxf(fmaxf(v1.x, v1.y), fmaxf(v1.z, v1.w)));
    #pragma unroll
    for (int off = 32; off; off >>= 1) m = fmaxf(m, __shfl_down(m, off, 64));

    __shared__ float red[4];
    const int wave = tid >> 6, lane = tid & 63;
    if (lane == 0) red[wave] = m;
    __syncthreads();
    m = fmaxf(fmaxf(red[0], red[1]), fmaxf(red[2], red[3]));
    __syncthreads();   // everyone has read red[] before it is reused

    // ---- block sum of exp ----
    float s = __expf(v0.x - m) + __expf(v0.y - m) + __expf(v0.z - m) + __expf(v0.w - m);
    if (has2)
        s += __expf(v1.x - m) + __expf(v1.y - m) + __expf(v1.z - m) + __expf(v1.w - m);
    #pragma unroll
    for (int off = 32; off; off >>= 1) s += __shfl_down(s, off, 64);
    if (lane == 0) red[wave] = s;
    __syncthreads();

    const float norm = m + __logf(red[0] + red[1] + red[2] + red[3]);

    // ---- gather extended labels: ext[l] = (l odd) ? targets[b][l>>1] : BLANK ----
    if (tid < LL) {
        const int lab = (tid & 1) ? targets[b * SS + (tid >> 1)] : 0;
        lp_ext[(size_t)bt * LP + tid] = row[lab] - norm;   // row[] is L1-hot
    }
}

// ---------------------------------------------------------------------------
// Kernel 2: CTC alpha recursion. One wave (64 lanes) per batch element.
// Lane l owns state l; lane 63 also owns state 64 (blank: no skip transition,
// feeds from states 63/64 only, both available on lane 63).
// No barriers — cross-state comms via shfl_up.
// ---------------------------------------------------------------------------
__global__ __launch_bounds__(64) void k_alpha(
    const float* __restrict__ lp_ext,
    const int* __restrict__ targets,
    const int* __restrict__ in_len,
    const int* __restrict__ tgt_len,
    float* __restrict__ partial)
{
    const int b    = blockIdx.x;
    const int lane = threadIdx.x;     // == state index (0..63)
    const float* lp = lp_ext + (size_t)b * TT * LP;
    const int Ti = in_len[b];
    const int Sb = tgt_len[b];

    // skip_ok for state=lane: odd state, label differs from label two back
    bool skip = false;
    if (lane & 1) {
        const int j = lane >> 1;
        skip = (j == 0) || (targets[b * SS + j] != targets[b * SS + j - 1]);
    }

    // t = 0 init
    float alpha   = (lane == 0) ? lp[0] : (lane == 1 ? lp[1] : NEGV);
    float alpha64 = NEGV;             // state 64, lane 63 only

    // prefetch t=1 row
    float lpc   = lp[LP + lane];
    float lpc64 = (lane == 63) ? lp[LP + 64] : 0.f;

    for (int t = 1; t < Ti; ++t) {
        const float lp_s  = lpc;
        const float lp_64 = lpc64;
        if (t + 1 < Ti) {
            lpc = lp[(size_t)(t + 1) * LP + lane];
            if (lane == 63) lpc64 = lp[(size_t)(t + 1) * LP + 64];
        }

        const float a1 = alpha;
        float a2 = __shfl_up(alpha, 1, 64);
        float a3 = __shfl_up(alpha, 2, 64);
        if (lane == 0) a2 = NEGV;
        if (!skip || lane < 2) a3 = NEGV;

        // state 64 (lane 63): a1 = old alpha64, a2 = old alpha[63] (== a1 local)
        if (lane == 63) {
            const float m2 = fmaxf(alpha64, a1);
            alpha64 = m2 + __logf(__expf(alpha64 - m2) + __expf(a1 - m2)) + lp_64;
        }

        const float mx = fmaxf(a1, fmaxf(a2, a3));
        alpha = mx + __logf(__expf(a1 - mx) + __expf(a2 - mx) + __expf(a3 - mx)) + lp_s;
    }

    // nll = -logaddexp(alpha[2Sb], alpha[2Sb-1])
    const float vll = __shfl(alpha, 2 * Sb - 1, 64);          // 2Sb-1 <= 63
    float vle;
    if (2 * Sb >= 64) vle = __shfl(alpha64, 63, 64);          // state 64 lives on lane 63
    else              vle = __shfl(alpha, 2 * Sb, 64);

    if (lane == 0) {
        const float mx = fmaxf(vle, vll);
        float nll = -(mx + __logf(__expf(vle - mx) + __expf(vll - mx)));
        if (isinf(nll) || nll > 1e29f) nll = 0.f;             // zero_infinity
        partial[b] = nll / (float)Sb;
    }
}

// ---------------------------------------------------------------------------
// Kernel 3: mean over batch -> scalar
// ---------------------------------------------------------------------------
__global__ __launch_bounds__(64) void k_mean(
    const float* __restrict__ partial, float* __restrict__ out)
{
    const int lane = threadIdx.x;
    float v = (lane < BB) ? partial[lane] : 0.f;
    #pragma unroll
    for (int off = 32; off; off >>= 1) v += __shfl_down(v, off, 64);
    if (lane == 0) out[0] = v / (float)BB;
}

extern "C" void kernel_launch(void* const* d_in, const int* in_sizes, int n_in,
                              void* d_out, int out_size, void* d_ws, size_t ws_size,
                              hipStream_t stream) {
    const float* logits   = (const float*)d_in[0];
    const int*   targets  = (const int*)d_in[1];
    const int*   in_len   = (const int*)d_in[2];
    const int*   tgt_len  = (const int*)d_in[3];
    float*       out      = (float*)d_out;

    // ws layout: [ lp_ext : B*T*LP floats ][ partial : B floats ]
    float* lp_ext  = (float*)d_ws;
    float* partial = lp_ext + (size_t)BB * TT * LP;

    k_lse_gather<<<BB * TT, 256, 0, stream>>>(logits, targets, lp_ext);
    k_alpha<<<BB, 64, 0, stream>>>(lp_ext, targets, in_len, tgt_len, partial);
    k_mean<<<1, 64, 0, stream>>>(partial, out);
}

// Round 3
// 293.175 us; speedup vs baseline: 1.5544x; 1.5544x over previous
//
#include <hip/hip_runtime.h>
#include <math.h>

// Problem constants (match reference setup_inputs)
#define BB 64
#define TT 512
#define VV 1296
#define SS 32
#define LL 65            // 2*S+1 extended labels
#define LP 72            // padded row stride for lp_ext
#define NEGV (-1e30f)
#define LOG2E 1.44269504088896340736f
#define LN2   0.69314718055994530942f

// raw v_exp_f32 (2^x) and v_log_f32 (log2 x)
#define EXP2(x) __builtin_amdgcn_exp2f(x)
#define LOG2(x) __builtin_amdgcn_logf(x)

// ---------------------------------------------------------------------------
// Kernel 1: one WAVE per (b,t) row — log-softmax normalizer + gather of the
// 65 extended-label log-probs (in log2 space) into ws. 4 rows per 256-block.
// No LDS, no syncthreads: butterfly shfl_xor reductions.
// Row = 1296 floats = 324 float4: lane loads f4 idx lane+64k (k<5); the last
// 4 float4s (320..323) are loaded by every lane at (320 + (lane&3)) — always
// in-bounds — and neutralized to -1e30 on lanes >= 4 (no inf: fast-math safe).
// ---------------------------------------------------------------------------
__global__ __launch_bounds__(256) void k_lse_gather(
    const float* __restrict__ logits,
    const int* __restrict__ targets,
    float* __restrict__ lp_ext)
{
    const int wid  = threadIdx.x >> 6;
    const int lane = threadIdx.x & 63;
    const int bt   = blockIdx.x * 4 + wid;       // row index, grid = BB*TT/4
    const int b    = bt >> 9;                    // TT = 512

    const float* row = logits + (size_t)bt * VV;
    const float4* row4 = (const float4*)row;

    float4 v[5];
    #pragma unroll
    for (int k = 0; k < 5; ++k) v[k] = row4[lane + 64 * k];
    float4 vx = row4[320 + (lane & 3)];          // in-bounds for every lane
    if (lane >= 4) { vx.x = NEGV; vx.y = NEGV; vx.z = NEGV; vx.w = NEGV; }

    // ---- wave max (butterfly: all lanes end with the max) ----
    float m = fmaxf(fmaxf(v[0].x, v[0].y), fmaxf(v[0].z, v[0].w));
    #pragma unroll
    for (int k = 1; k < 5; ++k)
        m = fmaxf(m, fmaxf(fmaxf(v[k].x, v[k].y), fmaxf(v[k].z, v[k].w)));
    m = fmaxf(m, fmaxf(fmaxf(vx.x, vx.y), fmaxf(vx.z, vx.w)));
    #pragma unroll
    for (int off = 1; off < 64; off <<= 1) m = fmaxf(m, __shfl_xor(m, off, 64));

    // ---- wave sum of exp (NEGV terms underflow to exactly 0) ----
    float s = 0.f;
    #pragma unroll
    for (int k = 0; k < 5; ++k)
        s += __expf(v[k].x - m) + __expf(v[k].y - m) +
             __expf(v[k].z - m) + __expf(v[k].w - m);
    s += __expf(vx.x - m) + __expf(vx.y - m) +
         __expf(vx.z - m) + __expf(vx.w - m);
    #pragma unroll
    for (int off = 1; off < 64; off <<= 1) s += __shfl_xor(s, off, 64);

    const float norm = m + __logf(s);            // natural-log normalizer

    // ---- gather extended labels, store in LOG2 space ----
    // ext[l] = (l odd) ? targets[b][l>>1] : BLANK(0); state 64 == state 0.
    const int lab = (lane & 1) ? targets[b * SS + (lane >> 1)] : 0;
    const float lp2 = (row[lab] - norm) * LOG2E;  // row[] is L1-hot
    float* dst = lp_ext + (size_t)bt * LP;
    dst[lane] = lp2;
    if (lane == 0) dst[64] = lp2;                // blank state 64 (unused now)
}

// ---------------------------------------------------------------------------
// Kernel 2: CTC alpha recursion in log2 space. One wave per batch element.
// Lane l owns state l; state 64 (final blank) is replicated on ALL lanes
// (update needs only alpha[63] broadcast + its own value -> no divergence).
// lp for state 64 == lp for state 0 (both blank) -> shfl from lane 0.
// Deep register FIFO (PF timesteps ahead) hides the ~600-900 cyc miss
// latency that dominated R1 (1066 cyc/step, VALUBusy 1.4%).
// NOTE: macro internals use trailing-underscore names — R2's NaN was the
// macro param shadowing its own local (`const float lp_s = (lp_s);` UB).
// ---------------------------------------------------------------------------
#define PF 12

__global__ __launch_bounds__(64) void k_alpha(
    const float* __restrict__ lp_ext,
    const int* __restrict__ targets,
    const int* __restrict__ in_len,
    const int* __restrict__ tgt_len,
    float* __restrict__ partial)
{
    const int b    = blockIdx.x;
    const int lane = threadIdx.x;                // == state index (0..63)
    const float* lp = lp_ext + (size_t)b * TT * LP;
    const int Ti = in_len[b];
    const int Sb = tgt_len[b];

    // skip transition allowed into state=lane (odd, label != label two back)
    bool skip = false;
    if ((lane & 1) && lane >= 3) {
        const int j = lane >> 1;
        skip = (targets[b * SS + j] != targets[b * SS + j - 1]);
    }

    // t = 0 init (lp already in log2 space)
    float alpha   = (lane == 0) ? lp[0] : (lane == 1 ? lp[1] : NEGV);
    float alpha64 = NEGV;                        // state 64, replicated

    // ---- prime the prefetch FIFO: buf[i] = lp row (t = 1+i) ----
    float buf[PF];
    #pragma unroll
    for (int i = 0; i < PF; ++i) {
        int tt = 1 + i; if (tt > TT - 1) tt = TT - 1;
        buf[i] = lp[(size_t)tt * LP + lane];
    }

    int t = 1;

#define STEP(LPS)                                                            \
    {                                                                        \
        const float lps_  = (LPS);                                           \
        const float lpbk_ = __shfl(lps_, 0, 64);       /* blank lp */        \
        const float a1_ = alpha;                                             \
        float a2_ = __shfl_up(alpha, 1, 64);                                 \
        float a3_ = __shfl_up(alpha, 2, 64);                                 \
        const float a63_ = __shfl(alpha, 63, 64);                            \
        if (lane == 0) a2_ = NEGV;                                           \
        if (lane < 2 || !skip) a3_ = NEGV;                                   \
        const float mx_ = fmaxf(a1_, fmaxf(a2_, a3_));                       \
        const float an_ = mx_ + LOG2(EXP2(a1_ - mx_) + EXP2(a2_ - mx_) +     \
                                     EXP2(a3_ - mx_)) + lps_;                \
        const float m2_ = fmaxf(alpha64, a63_);                              \
        alpha64 = m2_ + LOG2(EXP2(alpha64 - m2_) + EXP2(a63_ - m2_)) + lpbk_;\
        alpha = an_;                                                         \
    }

    // main loop: PF steps per outer iteration, prefetch PF ahead
    while (t + PF <= Ti) {
        #pragma unroll
        for (int i = 0; i < PF; ++i) {
            const float cur = buf[i];
            int tp = t + i + PF; if (tp > TT - 1) tp = TT - 1;
            buf[i] = lp[(size_t)tp * LP + lane];
            STEP(cur);
        }
        t += PF;
    }
    // tail: remaining (Ti - t) steps are in buf[0..]
    #pragma unroll
    for (int i = 0; i < PF; ++i) {
        if (t < Ti) { STEP(buf[i]); ++t; }
    }
#undef STEP

    // nll = -logaddexp(alpha[2Sb], alpha[2Sb-1])  (values in log2 space)
    const float vll = __shfl(alpha, 2 * Sb - 1, 64);      // 2Sb-1 <= 63
    const float vle = (2 * Sb >= 64) ? alpha64 : __shfl(alpha, 2 * Sb, 64);

    if (lane == 0) {
        const float mx = fmaxf(vle, vll);
        float nll = -LN2 * (mx + LOG2(EXP2(vle - mx) + EXP2(vll - mx)));
        if (isinf(nll) || nll > 1e29f) nll = 0.f;         // zero_infinity
        partial[b] = nll / (float)Sb;
    }
}

// ---------------------------------------------------------------------------
// Kernel 3: mean over batch -> scalar
// ---------------------------------------------------------------------------
__global__ __launch_bounds__(64) void k_mean(
    const float* __restrict__ partial, float* __restrict__ out)
{
    const int lane = threadIdx.x;
    float v = (lane < BB) ? partial[lane] : 0.f;
    #pragma unroll
    for (int off = 32; off; off >>= 1) v += __shfl_down(v, off, 64);
    if (lane == 0) out[0] = v / (float)BB;
}

extern "C" void kernel_launch(void* const* d_in, const int* in_sizes, int n_in,
                              void* d_out, int out_size, void* d_ws, size_t ws_size,
                              hipStream_t stream) {
    const float* logits   = (const float*)d_in[0];
    const int*   targets  = (const int*)d_in[1];
    const int*   in_len   = (const int*)d_in[2];
    const int*   tgt_len  = (const int*)d_in[3];
    float*       out      = (float*)d_out;

    // ws layout: [ lp_ext : B*T*LP floats ][ partial : B floats ]
    float* lp_ext  = (float*)d_ws;
    float* partial = lp_ext + (size_t)BB * TT * LP;

    k_lse_gather<<<BB * TT / 4, 256, 0, stream>>>(logits, targets, lp_ext);
    k_alpha<<<BB, 64, 0, stream>>>(lp_ext, targets, in_len, tgt_len, partial);
    k_mean<<<1, 64, 0, stream>>>(partial, out);
}